// Round 1
// baseline (789.119 us; speedup 1.0000x reference)
//
#include <hip/hip_runtime.h>

// Problem constants (fixed by the reference)
#define NN   50000
#define EE   800000
#define DD   64
#define HH   128
#define KIN  320          // 5 * 64
#define TILE_E 32         // 32 edges/block -> LDS 20480 B -> 8 blocks/CU (100% occupancy)

typedef __bf16 bf16x8 __attribute__((ext_vector_type(8)));
typedef float  f32x4  __attribute__((ext_vector_type(4)));

#if __has_builtin(__builtin_amdgcn_cvt_pk_bf16_f32)
typedef __bf16 bf16x2_t __attribute__((ext_vector_type(2)));
__device__ __forceinline__ unsigned int pk2(float a, float b) {
  union { bf16x2_t v; unsigned int u; } cv;
  cv.v = __builtin_amdgcn_cvt_pk_bf16_f32(a, b);
  return cv.u;
}
__device__ __forceinline__ unsigned short f2bf(float a) {
  return (unsigned short)(pk2(a, a) & 0xFFFFu);
}
#else
__device__ __forceinline__ unsigned short f2bf(float f) {
  union { float f; unsigned int u; } v; v.f = f;
  unsigned int u = v.u + 0x7FFFu + ((v.u >> 16) & 1u);   // RTNE
  return (unsigned short)(u >> 16);
}
__device__ __forceinline__ unsigned int pk2(float a, float b) {
  return (unsigned int)f2bf(a) | ((unsigned int)f2bf(b) << 16);
}
#endif

__device__ __forceinline__ float bf2f(unsigned short b) {
  union { unsigned int u; float f; } v; v.u = ((unsigned int)b) << 16; return v.f;
}

// ---------------------------------------------------------------------------
// Packed psi layout in 16B units, with a bank-spreading XOR swizzle:
//   raw unit = ((row>>4)*10 + (kk>>5))*64 + (row&15)*4 + ((kk>>3)&3)
//   swizzle:   unit ^= (unit>>4)&3   (bijective within each 1KiB block)
// The scalar u16 h1/h2 writebacks and epilogue reads have quad only in
// unit[5:4]; the XOR folds it into the bank bits (was an 8-bank hotspot,
// 2.8e7 conflict cycles). 16B-vector accesses cover whole 1KiB blocks and
// stay conflict-free under any intra-block permutation.
// ---------------------------------------------------------------------------
__device__ __forceinline__ int uaddr(int unit) {       // -> u16 index of unit
  return (unit ^ ((unit >> 4) & 3)) * 8;
}
__device__ __forceinline__ int psiIdx(int row, int kk) {
  int unit = (((row >> 4) * 10 + (kk >> 5)) << 6) + ((row & 15) << 2) + ((kk >> 3) & 3);
  return uaddr(unit) + (kk & 7);
}

// ---------------------------------------------------------------------------
// fp32 weights -> bf16, transposed to [n][k] so MFMA B-fragments are 16B runs.
// ---------------------------------------------------------------------------
__global__ __launch_bounds__(256) void prep_weights(
    const float* __restrict__ W0,
    const float* __restrict__ W1,
    const float* __restrict__ W2,
    unsigned short* __restrict__ WT0,
    unsigned short* __restrict__ WT1,
    unsigned short* __restrict__ WT2) {
  int t = blockIdx.x * 256 + threadIdx.x;
  if (t < KIN * HH) {
    int k = t / HH, n = t % HH;
    WT0[n * KIN + k] = f2bf(W0[t]);
  } else if (t < KIN * HH + HH * HH) {
    int u = t - KIN * HH; int k = u / HH, n = u % HH;
    WT1[n * HH + k] = f2bf(W1[u]);
  } else {
    int u = t - KIN * HH - HH * HH; int k = u / DD, n = u % DD;
    WT2[n * HH + k] = f2bf(W2[u]);
  }
}

// ---------------------------------------------------------------------------
// fp32 node tables -> bf16 tables (halves random-gather bytes in edge_mlp).
// ---------------------------------------------------------------------------
__global__ __launch_bounds__(256) void prep_tables(
    const float* __restrict__ hd, const float* __restrict__ hs,
    unsigned short* __restrict__ hdb, unsigned short* __restrict__ hsb) {
  int t = blockIdx.x * 256 + threadIdx.x;
  const int n = NN * DD / 8;              // 400000
  const float* src; unsigned short* dst; int i;
  if (t < n) { src = hd; dst = hdb; i = t; }
  else       { src = hs; dst = hsb; i = t - n; }
  float4 a = *(const float4*)(src + (size_t)i * 8);
  float4 b = *(const float4*)(src + (size_t)i * 8 + 4);
  uint4 w;
  w.x = pk2(a.x, a.y); w.y = pk2(a.z, a.w);
  w.z = pk2(b.x, b.y); w.w = pk2(b.z, b.w);
  *(uint4*)(dst + (size_t)i * 8) = w;
}

// ---------------------------------------------------------------------------
// Fused edge kernel. 256 threads (4 waves), 32 edges/block, LDS = 20480 B
// -> 8 blocks/CU (2048 threads = max). h1/h2 register-staged into the dead
// kk[0,128) region. Epilogue: scalar fp32 atomicAdd scatter.
// ---------------------------------------------------------------------------
__global__ __launch_bounds__(256, 8) void edge_mlp(
    const unsigned short* __restrict__ hdb,  // h_d_prev [N][64] bf16
    const unsigned short* __restrict__ hsb,  // h_s      [N][64] bf16
    const float* __restrict__ ef,            // edge_feat[E][64] fp32
    const int* __restrict__ snd,
    const int* __restrict__ rcv,
    const unsigned short* __restrict__ WT0,  // [128][320] bf16
    const float* __restrict__ b0,            // [128]
    const unsigned short* __restrict__ WT1,  // [128][128] bf16
    const float* __restrict__ b1,            // [128]
    const unsigned short* __restrict__ WT2,  // [64][128] bf16
    const float* __restrict__ b2,            // [64]
    float* __restrict__ agg)                 // [N][64] fp32
{
  __shared__ __align__(16) unsigned short psi[TILE_E * KIN];  // 20480 B exactly

  const int tid  = threadIdx.x;
  const int e0   = blockIdx.x * TILE_E;
  const int wv   = tid >> 6;
  const int lane = tid & 63;
  const int ln   = lane & 15;
  const int quad = lane >> 4;

  // Preload the 8 receiver indices this lane scatters to (hidden by gather).
  int ridx[8];
  #pragma unroll
  for (int mt = 0; mt < 2; ++mt)
    #pragma unroll
    for (int i = 0; i < 4; ++i)
      ridx[mt * 4 + i] = rcv[e0 + mt * 16 + quad * 4 + i];

  // Gather. 5 passes x 256 jobs: e = tid>>3 (32 edges), c = tid&7 (16B chunk).
  // segs 0-3: bf16 table rows (16B/job). seg 4: ef fp32, pack to bf16.
  {
    const int e = tid >> 3;
    const int c = tid & 7;
    #pragma unroll
    for (int seg = 0; seg < 5; ++seg) {
      int unit = (((e >> 4) * 10 + seg * 2 + (c >> 2)) << 6) + ((e & 15) << 2) + (c & 3);
      uint4 w;
      if (seg < 4) {
        const unsigned short* tb = (seg & 2) ? hdb : hsb;   // 0,1=h_s  2,3=h_d
        const int* ix = (seg & 1) ? rcv : snd;
        w = *(const uint4*)(tb + (size_t)ix[e0 + e] * DD + c * 8);
      } else {
        const float* src = ef + (size_t)(e0 + e) * DD;
        float4 v0 = *(const float4*)(src + c * 8);
        float4 v1 = *(const float4*)(src + c * 8 + 4);
        w.x = pk2(v0.x, v0.y); w.y = pk2(v0.z, v0.w);
        w.z = pk2(v1.x, v1.y); w.w = pk2(v1.z, v1.w);
      }
      *(uint4*)(&psi[uaddr(unit)]) = w;
    }
  }
  __syncthreads();

  f32x4 acc0[2], acc1[2];

  // ------------------ Layer 0: [32,320] @ [320,128] ------------------------
  {
    #pragma unroll
    for (int m = 0; m < 2; ++m) { acc0[m] = (f32x4){0,0,0,0}; acc1[m] = (f32x4){0,0,0,0}; }
    const unsigned short* wb0 = WT0 + (wv * 32 + ln) * KIN + quad * 8;
    const unsigned short* wb1 = wb0 + 16 * KIN;
    #pragma unroll
    for (int k0 = 0; k0 < 10; ++k0) {
      bf16x8 bf0 = *(const bf16x8*)(wb0 + k0 * 32);
      bf16x8 bf1 = *(const bf16x8*)(wb1 + k0 * 32);
      #pragma unroll
      for (int mt = 0; mt < 2; ++mt) {
        bf16x8 af = *(const bf16x8*)(&psi[uaddr(((mt * 10 + k0) << 6) + (ln << 2) + quad)]);
        acc0[mt] = __builtin_amdgcn_mfma_f32_16x16x32_bf16(af, bf0, acc0[mt], 0, 0, 0);
        acc1[mt] = __builtin_amdgcn_mfma_f32_16x16x32_bf16(af, bf1, acc1[mt], 0, 0, 0);
      }
    }
  }
  __syncthreads();          // psi input reads done -> safe to overwrite kk[0,128)

  // h1 -> kk [0,128)
  {
    float bv0 = b0[wv * 32 + ln];
    float bv1 = b0[wv * 32 + 16 + ln];
    #pragma unroll
    for (int mt = 0; mt < 2; ++mt) {
      #pragma unroll
      for (int i = 0; i < 4; ++i) {
        int base = ((mt * 10 + wv) << 6) + ((quad * 4 + i) << 2) + (ln >> 3);
        float v0 = acc0[mt][i] + bv0; v0 = v0 > 0.f ? v0 : 0.f;
        float v1 = acc1[mt][i] + bv1; v1 = v1 > 0.f ? v1 : 0.f;
        psi[uaddr(base)     + (ln & 7)] = f2bf(v0);
        psi[uaddr(base + 2) + (ln & 7)] = f2bf(v1);
      }
    }
  }
  __syncthreads();

  // ------------------ Layer 1: [32,128] @ [128,128] ------------------------
  {
    #pragma unroll
    for (int m = 0; m < 2; ++m) { acc0[m] = (f32x4){0,0,0,0}; acc1[m] = (f32x4){0,0,0,0}; }
    const unsigned short* wb0 = WT1 + (wv * 32 + ln) * HH + quad * 8;
    const unsigned short* wb1 = wb0 + 16 * HH;
    #pragma unroll
    for (int k0 = 0; k0 < 4; ++k0) {
      bf16x8 bf0 = *(const bf16x8*)(wb0 + k0 * 32);
      bf16x8 bf1 = *(const bf16x8*)(wb1 + k0 * 32);
      #pragma unroll
      for (int mt = 0; mt < 2; ++mt) {
        bf16x8 af = *(const bf16x8*)(&psi[uaddr(((mt * 10 + k0) << 6) + (ln << 2) + quad)]);
        acc0[mt] = __builtin_amdgcn_mfma_f32_16x16x32_bf16(af, bf0, acc0[mt], 0, 0, 0);
        acc1[mt] = __builtin_amdgcn_mfma_f32_16x16x32_bf16(af, bf1, acc1[mt], 0, 0, 0);
      }
    }
  }
  __syncthreads();          // h1 reads done -> overwrite with h2

  {
    float bv0 = b1[wv * 32 + ln];
    float bv1 = b1[wv * 32 + 16 + ln];
    #pragma unroll
    for (int mt = 0; mt < 2; ++mt) {
      #pragma unroll
      for (int i = 0; i < 4; ++i) {
        int base = ((mt * 10 + wv) << 6) + ((quad * 4 + i) << 2) + (ln >> 3);
        float v0 = acc0[mt][i] + bv0; v0 = v0 > 0.f ? v0 : 0.f;
        float v1 = acc1[mt][i] + bv1; v1 = v1 > 0.f ? v1 : 0.f;
        psi[uaddr(base)     + (ln & 7)] = f2bf(v0);
        psi[uaddr(base + 2) + (ln & 7)] = f2bf(v1);
      }
    }
  }
  __syncthreads();

  // ---------- Layer 2: [32,128] @ [128,64] + s_ij + atomic scatter ---------
  {
    f32x4 acc[2];
    #pragma unroll
    for (int m = 0; m < 2; ++m) acc[m] = (f32x4){0,0,0,0};
    const unsigned short* wb = WT2 + (wv * 16 + ln) * HH + quad * 8;
    #pragma unroll
    for (int k0 = 0; k0 < 4; ++k0) {
      bf16x8 bf = *(const bf16x8*)(wb + k0 * 32);
      #pragma unroll
      for (int mt = 0; mt < 2; ++mt) {
        bf16x8 af = *(const bf16x8*)(&psi[uaddr(((mt * 10 + k0) << 6) + (ln << 2) + quad)]);
        acc[mt] = __builtin_amdgcn_mfma_f32_16x16x32_bf16(af, bf, acc[mt], 0, 0, 0);
      }
    }
    int   col = wv * 16 + ln;   // waves 0..3 cover cols 0..63
    float bv  = b2[col];
    #pragma unroll
    for (int mt = 0; mt < 2; ++mt) {
      #pragma unroll
      for (int i = 0; i < 4; ++i) {
        int row = mt * 16 + quad * 4 + i;
        float p  = acc[mt][i] + bv; p = p > 0.f ? p : 0.f;
        float di = bf2f(psi[psiIdx(row, 128 + col)]);
        float dj = bf2f(psi[psiIdx(row, 192 + col)]);
        float s  = p * (dj - di);
        atomicAdd(&agg[(size_t)ridx[mt * 4 + i] * DD + col], s);
      }
    }
  }
}

// ---------------------------------------------------------------------------
// out = h_d_prev + agg @ Wm  (fp32). 16 rows/block, LDS-staged agg (stride 72
// swizzle: conflict-free broadcast) + float4 Wm reads. Grid 3125.
// ---------------------------------------------------------------------------
__global__ __launch_bounds__(256) void final_out(
    const float* __restrict__ hd,
    const float* __restrict__ agg,
    const float* __restrict__ Wm,   // [64][64] fp32
    float* __restrict__ out)
{
  __shared__ float wmf[DD * DD];    // 16 KB
  __shared__ float arow[16 * 72];   // 4.5 KB, stride-72 swizzle
  int tid = threadIdx.x;
  const float4* wm4 = (const float4*)Wm;
  float4* wf4 = (float4*)wmf;
  #pragma unroll
  for (int i = tid; i < DD * DD / 4; i += 256) wf4[i] = wm4[i];

  int r0 = blockIdx.x * 16;
  {
    float4 av = *(const float4*)(agg + (size_t)r0 * DD + tid * 4);
    int rr = tid >> 4, cc = (tid & 15) * 4;       // tid*4 == rr*64 + cc
    *(float4*)&arow[rr * 72 + cc] = av;
  }
  __syncthreads();

  int row = tid >> 4;
  int cq  = (tid & 15) * 4;
  f32x4 acc = (f32x4){0, 0, 0, 0};
  #pragma unroll
  for (int k = 0; k < DD; ++k) {
    float a = arow[row * 72 + k];
    f32x4 w = *(const f32x4*)&wmf[k * DD + cq];
    acc += a * w;
  }
  size_t o = ((size_t)(r0 + row)) * DD + cq;
  f32x4 h = *(const f32x4*)(hd + o);
  *(f32x4*)(out + o) = h + acc;
}

// ---------------------------------------------------------------------------
extern "C" void kernel_launch(void* const* d_in, const int* in_sizes, int n_in,
                              void* d_out, int out_size, void* d_ws, size_t ws_size,
                              hipStream_t stream) {
  const float* hd = (const float*)d_in[0];
  const float* hs = (const float*)d_in[1];
  const float* ef = (const float*)d_in[2];
  const int* snd  = (const int*)d_in[3];
  const int* rcv  = (const int*)d_in[4];
  const float* W0 = (const float*)d_in[5];
  const float* b0 = (const float*)d_in[6];
  const float* W1 = (const float*)d_in[7];
  const float* b1 = (const float*)d_in[8];
  const float* W2 = (const float*)d_in[9];
  const float* b2 = (const float*)d_in[10];
  const float* Wm = (const float*)d_in[11];
  float* out      = (float*)d_out;

  char* ws = (char*)d_ws;
  float* agg = (float*)ws;                                   // 12,800,000 B
  unsigned short* WT0 = (unsigned short*)(ws + 12800000);    // 81,920 B
  unsigned short* WT1 = WT0 + KIN * HH;                      // 32,768 B
  unsigned short* WT2 = WT1 + HH * HH;                       // 16,384 B
  unsigned short* hdb = WT2 + HH * DD;                       // 6,400,000 B
  unsigned short* hsb = hdb + (size_t)NN * DD;               // 6,400,000 B
                                                             // total ~25.8 MB
  hipMemsetAsync(agg, 0, (size_t)NN * DD * sizeof(float), stream);
  prep_weights<<<256, 256, 0, stream>>>(W0, W1, W2, WT0, WT1, WT2);
  prep_tables<<<NN * DD * 2 / 8 / 256, 256, 0, stream>>>(hd, hs, hdb, hsb);
  edge_mlp<<<EE / TILE_E, 256, 0, stream>>>(hdb, hsb, ef, snd, rcv,
                                            WT0, b0, WT1, b1, WT2, b2, agg);
  final_out<<<NN / 16, 256, 0, stream>>>(hd, agg, Wm, out);
}

// Round 2
// 683.108 us; speedup vs baseline: 1.1552x; 1.1552x over previous
//
#include <hip/hip_runtime.h>

// Problem constants (fixed by the reference)
#define NN   50000
#define EE   800000
#define DD   64
#define HH   128
#define KIN  320          // 5 * 64
#define TILE_E 64

typedef __bf16 bf16x8 __attribute__((ext_vector_type(8)));
typedef float  f32x4  __attribute__((ext_vector_type(4)));

#if __has_builtin(__builtin_amdgcn_cvt_pk_bf16_f32)
typedef __bf16 bf16x2_t __attribute__((ext_vector_type(2)));
__device__ __forceinline__ unsigned int pk2(float a, float b) {
  union { bf16x2_t v; unsigned int u; } cv;
  cv.v = __builtin_amdgcn_cvt_pk_bf16_f32(a, b);
  return cv.u;
}
__device__ __forceinline__ unsigned short f2bf(float a) {
  return (unsigned short)(pk2(a, a) & 0xFFFFu);
}
#else
__device__ __forceinline__ unsigned short f2bf(float f) {
  union { float f; unsigned int u; } v; v.f = f;
  unsigned int u = v.u + 0x7FFFu + ((v.u >> 16) & 1u);   // RTNE
  return (unsigned short)(u >> 16);
}
__device__ __forceinline__ unsigned int pk2(float a, float b) {
  return (unsigned int)f2bf(a) | ((unsigned int)f2bf(b) << 16);
}
#endif

__device__ __forceinline__ float bf2f(unsigned short b) {
  union { unsigned int u; float f; } v; v.u = ((unsigned int)b) << 16; return v.f;
}

// Packed, pad-free psi layout in 16B units: unit = (mt*10 + k0)*64 + row15*4 + quad
// u16 index for (row in [0,64), kk in [0,320)):
__device__ __forceinline__ int psiIdx(int row, int kk) {
  return ((((row >> 4) * 10 + (kk >> 5)) << 6) + ((row & 15) << 2) + ((kk >> 3) & 3)) * 8
         + (kk & 7);
}

// ---------------------------------------------------------------------------
// fp32 weights -> bf16, transposed to [n][k] so MFMA B-fragments are 16B runs.
// ---------------------------------------------------------------------------
__global__ __launch_bounds__(256) void prep_weights(
    const float* __restrict__ W0,
    const float* __restrict__ W1,
    const float* __restrict__ W2,
    unsigned short* __restrict__ WT0,
    unsigned short* __restrict__ WT1,
    unsigned short* __restrict__ WT2) {
  int t = blockIdx.x * 256 + threadIdx.x;
  if (t < KIN * HH) {
    int k = t / HH, n = t % HH;
    WT0[n * KIN + k] = f2bf(W0[t]);
  } else if (t < KIN * HH + HH * HH) {
    int u = t - KIN * HH; int k = u / HH, n = u % HH;
    WT1[n * HH + k] = f2bf(W1[u]);
  } else {
    int u = t - KIN * HH - HH * HH; int k = u / DD, n = u % DD;
    WT2[n * HH + k] = f2bf(W2[u]);
  }
}

// ---------------------------------------------------------------------------
// fp32 node tables -> bf16 tables + fused receiver histogram (t == edge id).
// 800000 jobs; grid 3125 x 256.
// ---------------------------------------------------------------------------
__global__ __launch_bounds__(256) void prep_tables(
    const float* __restrict__ hd, const float* __restrict__ hs,
    unsigned short* __restrict__ hdb, unsigned short* __restrict__ hsb,
    const int* __restrict__ rcv, int* __restrict__ cnt) {
  int t = blockIdx.x * 256 + threadIdx.x;
  atomicAdd(&cnt[rcv[t]], 1);             // histogram for counting sort
  const int n = NN * DD / 8;              // 400000
  const float* src; unsigned short* dst; int i;
  if (t < n) { src = hd; dst = hdb; i = t; }
  else       { src = hs; dst = hsb; i = t - n; }
  float4 a = *(const float4*)(src + (size_t)i * 8);
  float4 b = *(const float4*)(src + (size_t)i * 8 + 4);
  uint4 w;
  w.x = pk2(a.x, a.y); w.y = pk2(a.z, a.w);
  w.z = pk2(b.x, b.y); w.w = pk2(b.z, b.w);
  *(uint4*)(dst + (size_t)i * 8) = w;
}

// ---------------------------------------------------------------------------
// Exclusive prefix sum over cnt[50000] in place. One block, 1024 threads.
// ---------------------------------------------------------------------------
__global__ __launch_bounds__(1024) void scan_bins(int* __restrict__ cnt) {
  __shared__ int ts[1024];
  const int C = 49;                       // 1024*49 >= 50000
  int t = threadIdx.x;
  int base = t * C;
  int s = 0;
  for (int i = 0; i < C; ++i) { int idx = base + i; if (idx < NN) s += cnt[idx]; }
  ts[t] = s;
  __syncthreads();
  for (int d = 1; d < 1024; d <<= 1) {    // Hillis-Steele inclusive scan
    int v = (t >= d) ? ts[t - d] : 0;
    __syncthreads();
    ts[t] += v;
    __syncthreads();
  }
  int run = (t == 0) ? 0 : ts[t - 1];
  for (int i = 0; i < C; ++i) {
    int idx = base + i;
    if (idx < NN) { int c = cnt[idx]; cnt[idx] = run; run += c; }
  }
}

// ---------------------------------------------------------------------------
// Counting-sort scatter: perm (sorted->orig edge), plus pre-gathered
// rsorted/ssorted so edge_mlp index reads are linear.
// ---------------------------------------------------------------------------
__global__ __launch_bounds__(256) void scatter_perm(
    const int* __restrict__ snd, const int* __restrict__ rcv,
    const int* __restrict__ cnt, int* __restrict__ cursor,
    int* __restrict__ perm, int* __restrict__ rsorted, int* __restrict__ ssorted) {
  int e = blockIdx.x * 256 + threadIdx.x;
  int r = rcv[e];
  int pos = cnt[r] + atomicAdd(&cursor[r], 1);
  perm[pos]    = e;
  rsorted[pos] = r;
  ssorted[pos] = snd[e];
}

// ---------------------------------------------------------------------------
// Fused edge kernel, receiver-sorted order. 256 threads (4 waves), 64 edges/
// block, LDS = 40960 B -> 4 blocks/CU. Epilogue: s_ij -> LDS fp32 tile
// (overlaid on psi) -> run-merged atomic scatter (sorted receivers =>
// ~8x fewer atomics, agg rows touched by 1-2 blocks instead of 8 XCDs).
// ---------------------------------------------------------------------------
__global__ __launch_bounds__(256, 4) void edge_mlp(
    const unsigned short* __restrict__ hdb,  // h_d_prev [N][64] bf16
    const unsigned short* __restrict__ hsb,  // h_s      [N][64] bf16
    const float* __restrict__ ef,            // edge_feat[E][64] fp32
    const int* __restrict__ perm,            // sorted -> original edge id
    const int* __restrict__ rsorted,         // receiver per sorted edge
    const int* __restrict__ ssorted,         // sender   per sorted edge
    const unsigned short* __restrict__ WT0,  // [128][320] bf16
    const float* __restrict__ b0,            // [128]
    const unsigned short* __restrict__ WT1,  // [128][128] bf16
    const float* __restrict__ b1,            // [128]
    const unsigned short* __restrict__ WT2,  // [64][128] bf16
    const float* __restrict__ b2,            // [64]
    float* __restrict__ agg)                 // [N][64] fp32
{
  __shared__ __align__(16) unsigned short psi[TILE_E * KIN];  // 40960 B exactly

  const int tid  = threadIdx.x;
  const int e0   = blockIdx.x * TILE_E;
  const int wv   = tid >> 6;
  const int lane = tid & 63;
  const int ln   = lane & 15;
  const int quad = lane >> 4;

  // Early receiver load for the merge phase (hidden under the gather).
  int myr = 0;
  if (tid < TILE_E) myr = rsorted[e0 + tid];

  // Gather. segs 0-3: bf16 table rows (16B/job). seg 4: ef fp32 (via perm).
  #pragma unroll
  for (int i = 0; i < 10; ++i) {
    const int seg = i >> 1;                    // compile-time 0..4
    int e = ((i << 5) + (tid >> 3)) & 63;      // edge within tile
    int c = tid & 7;                           // 16B chunk of the row
    int unit = (((e >> 4) * 10 + seg * 2 + (c >> 2)) << 6) + ((e & 15) << 2) + (c & 3);
    uint4 w;
    if (seg < 4) {
      const unsigned short* tb = (seg & 2) ? hdb : hsb;   // 0,1=h_s  2,3=h_d
      const int* ix = (seg & 1) ? rsorted : ssorted;
      w = *(const uint4*)(tb + (size_t)ix[e0 + e] * DD + c * 8);
    } else {
      int re = perm[e0 + e];
      const float* src = ef + (size_t)re * DD;
      float4 v0 = *(const float4*)(src + c * 8);
      float4 v1 = *(const float4*)(src + c * 8 + 4);
      w.x = pk2(v0.x, v0.y); w.y = pk2(v0.z, v0.w);
      w.z = pk2(v1.x, v1.y); w.w = pk2(v1.z, v1.w);
    }
    *(uint4*)(&psi[unit * 8]) = w;
  }
  __syncthreads();

  f32x4 acc0[4], acc1[4];

  // ------------------ Layer 0: [64,320] @ [320,128] ------------------------
  {
    #pragma unroll
    for (int m = 0; m < 4; ++m) { acc0[m] = (f32x4){0,0,0,0}; acc1[m] = (f32x4){0,0,0,0}; }
    const unsigned short* wb0 = WT0 + (wv * 32 + ln) * KIN + quad * 8;
    const unsigned short* wb1 = wb0 + 16 * KIN;
    #pragma unroll
    for (int k0 = 0; k0 < 10; ++k0) {
      bf16x8 bf0 = *(const bf16x8*)(wb0 + k0 * 32);
      bf16x8 bf1 = *(const bf16x8*)(wb1 + k0 * 32);
      #pragma unroll
      for (int mt = 0; mt < 4; ++mt) {
        bf16x8 af = *(const bf16x8*)(&psi[(((mt * 10 + k0) << 6) + (ln << 2) + quad) * 8]);
        acc0[mt] = __builtin_amdgcn_mfma_f32_16x16x32_bf16(af, bf0, acc0[mt], 0, 0, 0);
        acc1[mt] = __builtin_amdgcn_mfma_f32_16x16x32_bf16(af, bf1, acc1[mt], 0, 0, 0);
      }
    }
  }
  __syncthreads();          // psi input reads done -> safe to overwrite kk[0,128)

  // h1 -> kk [0,128)
  {
    float bv0 = b0[wv * 32 + ln];
    float bv1 = b0[wv * 32 + 16 + ln];
    #pragma unroll
    for (int mt = 0; mt < 4; ++mt) {
      #pragma unroll
      for (int i = 0; i < 4; ++i) {
        int base = ((mt * 10 + wv) << 6) + ((quad * 4 + i) << 2) + (ln >> 3);
        float v0 = acc0[mt][i] + bv0; v0 = v0 > 0.f ? v0 : 0.f;
        float v1 = acc1[mt][i] + bv1; v1 = v1 > 0.f ? v1 : 0.f;
        psi[base * 8 + (ln & 7)]       = f2bf(v0);
        psi[(base + 2) * 8 + (ln & 7)] = f2bf(v1);
      }
    }
  }
  __syncthreads();

  // ------------------ Layer 1: [64,128] @ [128,128] ------------------------
  {
    #pragma unroll
    for (int m = 0; m < 4; ++m) { acc0[m] = (f32x4){0,0,0,0}; acc1[m] = (f32x4){0,0,0,0}; }
    const unsigned short* wb0 = WT1 + (wv * 32 + ln) * HH + quad * 8;
    const unsigned short* wb1 = wb0 + 16 * HH;
    #pragma unroll
    for (int k0 = 0; k0 < 4; ++k0) {
      bf16x8 bf0 = *(const bf16x8*)(wb0 + k0 * 32);
      bf16x8 bf1 = *(const bf16x8*)(wb1 + k0 * 32);
      #pragma unroll
      for (int mt = 0; mt < 4; ++mt) {
        bf16x8 af = *(const bf16x8*)(&psi[(((mt * 10 + k0) << 6) + (ln << 2) + quad) * 8]);
        acc0[mt] = __builtin_amdgcn_mfma_f32_16x16x32_bf16(af, bf0, acc0[mt], 0, 0, 0);
        acc1[mt] = __builtin_amdgcn_mfma_f32_16x16x32_bf16(af, bf1, acc1[mt], 0, 0, 0);
      }
    }
  }
  __syncthreads();          // h1 reads done -> overwrite with h2

  {
    float bv0 = b1[wv * 32 + ln];
    float bv1 = b1[wv * 32 + 16 + ln];
    #pragma unroll
    for (int mt = 0; mt < 4; ++mt) {
      #pragma unroll
      for (int i = 0; i < 4; ++i) {
        int base = ((mt * 10 + wv) << 6) + ((quad * 4 + i) << 2) + (ln >> 3);
        float v0 = acc0[mt][i] + bv0; v0 = v0 > 0.f ? v0 : 0.f;
        float v1 = acc1[mt][i] + bv1; v1 = v1 > 0.f ? v1 : 0.f;
        psi[base * 8 + (ln & 7)]       = f2bf(v0);
        psi[(base + 2) * 8 + (ln & 7)] = f2bf(v1);
      }
    }
  }
  __syncthreads();

  // ---- Layer 2: [64,128] @ [128,64] + s_ij + run-merged atomic scatter ----
  {
    f32x4 acc[4];
    #pragma unroll
    for (int m = 0; m < 4; ++m) acc[m] = (f32x4){0,0,0,0};
    const unsigned short* wb = WT2 + (wv * 16 + ln) * HH + quad * 8;
    #pragma unroll
    for (int k0 = 0; k0 < 4; ++k0) {
      bf16x8 bf = *(const bf16x8*)(wb + k0 * 32);
      #pragma unroll
      for (int mt = 0; mt < 4; ++mt) {
        bf16x8 af = *(const bf16x8*)(&psi[(((mt * 10 + k0) << 6) + (ln << 2) + quad) * 8]);
        acc[mt] = __builtin_amdgcn_mfma_f32_16x16x32_bf16(af, bf, acc[mt], 0, 0, 0);
      }
    }
    int   col = wv * 16 + ln;   // waves 0..3 cover cols 0..63
    float bv  = b2[col];
    float sv[16];
    #pragma unroll
    for (int mt = 0; mt < 4; ++mt) {
      #pragma unroll
      for (int i = 0; i < 4; ++i) {
        int row = mt * 16 + quad * 4 + i;
        float p  = acc[mt][i] + bv; p = p > 0.f ? p : 0.f;
        float di = bf2f(psi[psiIdx(row, 128 + col)]);
        float dj = bf2f(psi[psiIdx(row, 192 + col)]);
        sv[mt * 4 + i] = p * (dj - di);
      }
    }
    __syncthreads();          // all psi reads done -> overlay s-tile + rt

    float* st = (float*)psi;                   // [64][64] fp32, 16384 B
    int*   rt = (int*)(psi + 8192);            // 64 ints at byte 16384
    #pragma unroll
    for (int mt = 0; mt < 4; ++mt) {
      #pragma unroll
      for (int i = 0; i < 4; ++i) {
        int row = mt * 16 + quad * 4 + i;      // (row>>2)&3 == quad
        st[row * 64 + (col ^ (quad << 3))] = sv[mt * 4 + i];
      }
    }
    if (tid < TILE_E) rt[tid] = myr;
    __syncthreads();

    // Thread t: column c2 = t&63, rows [wv*16, wv*16+16), sorted receivers.
    // rt[row] is wave-uniform per step -> no divergence in the run-merge.
    int c2  = tid & 63;
    int rr0 = (tid >> 6) * 16;
    float a  = 0.f;
    int  prev = rt[rr0];
    #pragma unroll
    for (int j = 0; j < 16; ++j) {
      int row = rr0 + j;
      int rc  = rt[row];
      float v = st[row * 64 + (c2 ^ ((((unsigned)row >> 2) & 3) << 3))];
      if (rc != prev) {
        atomicAdd(&agg[(size_t)prev * DD + c2], a);
        a = v; prev = rc;
      } else {
        a += v;
      }
    }
    atomicAdd(&agg[(size_t)prev * DD + c2], a);
  }
}

// ---------------------------------------------------------------------------
// out = h_d_prev + agg @ Wm  (fp32). 16 rows/block, LDS-staged agg (stride 72
// swizzle: conflict-free broadcast) + float4 Wm reads. Grid 3125.
// ---------------------------------------------------------------------------
__global__ __launch_bounds__(256) void final_out(
    const float* __restrict__ hd,
    const float* __restrict__ agg,
    const float* __restrict__ Wm,   // [64][64] fp32
    float* __restrict__ out)
{
  __shared__ float wmf[DD * DD];    // 16 KB
  __shared__ float arow[16 * 72];   // 4.5 KB, stride-72 swizzle
  int tid = threadIdx.x;
  const float4* wm4 = (const float4*)Wm;
  float4* wf4 = (float4*)wmf;
  #pragma unroll
  for (int i = tid; i < DD * DD / 4; i += 256) wf4[i] = wm4[i];

  int r0 = blockIdx.x * 16;
  {
    float4 av = *(const float4*)(agg + (size_t)r0 * DD + tid * 4);
    int rr = tid >> 4, cc = (tid & 15) * 4;       // tid*4 == rr*64 + cc
    *(float4*)&arow[rr * 72 + cc] = av;
  }
  __syncthreads();

  int row = tid >> 4;
  int cq  = (tid & 15) * 4;
  f32x4 acc = (f32x4){0, 0, 0, 0};
  #pragma unroll
  for (int k = 0; k < DD; ++k) {
    float a = arow[row * 72 + k];
    f32x4 w = *(const f32x4*)&wmf[k * DD + cq];
    acc += a * w;
  }
  size_t o = ((size_t)(r0 + row)) * DD + cq;
  f32x4 h = *(const f32x4*)(hd + o);
  *(f32x4*)(out + o) = h + acc;
}

// ---------------------------------------------------------------------------
extern "C" void kernel_launch(void* const* d_in, const int* in_sizes, int n_in,
                              void* d_out, int out_size, void* d_ws, size_t ws_size,
                              hipStream_t stream) {
  const float* hd = (const float*)d_in[0];
  const float* hs = (const float*)d_in[1];
  const float* ef = (const float*)d_in[2];
  const int* snd  = (const int*)d_in[3];
  const int* rcv  = (const int*)d_in[4];
  const float* W0 = (const float*)d_in[5];
  const float* b0 = (const float*)d_in[6];
  const float* W1 = (const float*)d_in[7];
  const float* b1 = (const float*)d_in[8];
  const float* W2 = (const float*)d_in[9];
  const float* b2 = (const float*)d_in[10];
  const float* Wm = (const float*)d_in[11];
  float* out      = (float*)d_out;

  char* ws = (char*)d_ws;
  float* agg  = (float*)ws;                                  // 12,800,000 B
  int* cnt    = (int*)(ws + 12800000);                       //    200,000 B
  int* cursor = (int*)(ws + 13000000);                       //    200,000 B
  unsigned short* WT0 = (unsigned short*)(ws + 13200000);    //     81,920 B
  unsigned short* WT1 = WT0 + KIN * HH;                      //     32,768 B
  unsigned short* WT2 = WT1 + HH * HH;                       //     16,384 B
  int* perm    = (int*)(ws + 13331072);                      //  3,200,000 B
  int* rsorted = perm + EE;                                  //  3,200,000 B
  int* ssorted = rsorted + EE;                               //  3,200,000 B
  unsigned short* hdb = (unsigned short*)(ssorted + EE);     //  6,400,000 B
  unsigned short* hsb = hdb + (size_t)NN * DD;               //  6,400,000 B
                                                             // total ~35.7 MB
  hipMemsetAsync(ws, 0, 13200000, stream);   // agg + cnt + cursor
  prep_weights<<<256, 256, 0, stream>>>(W0, W1, W2, WT0, WT1, WT2);
  prep_tables<<<NN * DD * 2 / 8 / 256, 256, 0, stream>>>(hd, hs, hdb, hsb, rcv, cnt);
  scan_bins<<<1, 1024, 0, stream>>>(cnt);
  scatter_perm<<<EE / 256, 256, 0, stream>>>(snd, rcv, cnt, cursor,
                                             perm, rsorted, ssorted);
  edge_mlp<<<EE / TILE_E, 256, 0, stream>>>(hdb, hsb, ef, perm, rsorted, ssorted,
                                            WT0, b0, WT1, b1, WT2, b2, agg);
  final_out<<<NN / 16, 256, 0, stream>>>(hd, agg, Wm, out);
}